// Round 1
// baseline (758.401 us; speedup 1.0000x reference)
//
#include <hip/hip_runtime.h>

#define N 8192
#define DIN 128
#define DH 48
#define MT 64            // rows per k_gat block
#define KC 128           // j-chunk
#define NSPLIT 8         // K-splits over j
#define JSPAN (N / NSPLIT)   // 1024
#define ACC_STRIDE 52    // 48 dims + l, padded to 16B multiple
#define RB 32            // rows per k_mlp block

// ---------------- Kernel 1a: Wh = x @ Wgat^T  [8192,128]x[48,128] -> [8192,48]
__global__ __launch_bounds__(256) void k_wh(const float* __restrict__ x,
                                            const float* __restrict__ Wg,
                                            float* __restrict__ Wh) {
    __shared__ float wT[DIN * DH];  // transposed: wT[k*DH + c] = Wg[c*DIN + k]
    int t = threadIdx.x;
    for (int e = t; e < DIN * DH; e += 256) {
        int c = e / DIN, k = e % DIN;
        wT[k * DH + c] = Wg[e];
    }
    __syncthreads();
    int o = blockIdx.x * 256 + t;      // o < 8192*48
    int r = o / DH, c = o % DH;
    const float4* xr = (const float4*)(x + (size_t)r * DIN);
    float acc = 0.f;
    #pragma unroll 8
    for (int k4 = 0; k4 < DIN / 4; ++k4) {
        float4 xv = xr[k4];
        int kb = k4 * 4;
        acc += xv.x * wT[(kb + 0) * DH + c];
        acc += xv.y * wT[(kb + 1) * DH + c];
        acc += xv.z * wT[(kb + 2) * DH + c];
        acc += xv.w * wT[(kb + 3) * DH + c];
    }
    Wh[o] = acc;
}

// ---------------- Kernel 1b: s = Wh @ a^T
__global__ __launch_bounds__(256) void k_s(const float* __restrict__ Wh,
                                           const float* __restrict__ a,
                                           float* __restrict__ s) {
    int r = blockIdx.x * 256 + threadIdx.x;
    const float4* wr = (const float4*)(Wh + (size_t)r * DH);
    const float4* av = (const float4*)a;
    float acc = 0.f;
    #pragma unroll
    for (int k4 = 0; k4 < DH / 4; ++k4) {
        float4 w = wr[k4]; float4 aa = av[k4];
        acc += w.x * aa.x + w.y * aa.y + w.z * aa.z + w.w * aa.w;
    }
    s[r] = acc;
}

// ---------------- Kernel 2: fused masked-softmax attention (no max-sub needed:
// e bounded ~|2|), K-split partial sums. Block: 64 rows x JSPAN j's.
__global__ __launch_bounds__(256) void k_gat(const int* __restrict__ adj,
                                             const float* __restrict__ Wh,
                                             const float* __restrict__ s,
                                             float* __restrict__ accWs) {
    __shared__ float pT[KC][MT + 1];   // [j][row], padded: 2-way banks max
    __shared__ float sRow[MT];
    int t = threadIdx.x;
    int tile = blockIdx.x & 127;       // 128 row tiles
    int split = blockIdx.x >> 7;       // 0..NSPLIT-1
    int i0 = tile * MT;
    int jbase = split * JSPAN;

    if (t < MT) sRow[t] = s[i0 + t];

    int lane = t & 63;                 // MAC: row within tile
    int w = t >> 6;                    // MAC: wave -> 12-dim slice
    int jl = t & 127;                  // phase A: column
    int rg = t >> 7;                   // phase A: row group (0/1)

    float acc[12];
    #pragma unroll
    for (int d = 0; d < 12; ++d) acc[d] = 0.f;
    float lsum = 0.f;

    __syncthreads();

    for (int chunk = 0; chunk < JSPAN / KC; ++chunk) {
        int j0 = jbase + chunk * KC;
        // ---- phase A: p[j][i] for this chunk (coalesced adj stream)
        float sj = s[j0 + jl];
        #pragma unroll 4
        for (int it = 0; it < MT / 2; ++it) {
            int r = rg + 2 * it;
            int av = adj[(size_t)(i0 + r) * N + (j0 + jl)];
            float e = sRow[r] + sj;
            e = fmaxf(e, 0.2f * e);               // LeakyReLU(0.2) exactly
            float p = (av > 0) ? __expf(e) : 0.f; // masked -> exact 0
            pT[jl][r] = p;
        }
        __syncthreads();
        // ---- MAC: acc[i][d] += p * Wh[j][d]; Wh uniform-per-wave from L2
        const float* wbase = Wh + (size_t)j0 * DH + w * 12;
        #pragma unroll 4
        for (int jj = 0; jj < KC; ++jj) {
            float p = pT[jj][lane];
            const float4* wr = (const float4*)(wbase + jj * DH);
            float4 w0 = wr[0], w1 = wr[1], w2 = wr[2];
            acc[0] += p * w0.x; acc[1] += p * w0.y; acc[2]  += p * w0.z; acc[3]  += p * w0.w;
            acc[4] += p * w1.x; acc[5] += p * w1.y; acc[6]  += p * w1.z; acc[7]  += p * w1.w;
            acc[8] += p * w2.x; acc[9] += p * w2.y; acc[10] += p * w2.z; acc[11] += p * w2.w;
            lsum += p;
        }
        __syncthreads();
    }
    float* orow = accWs + ((size_t)split * N + i0 + lane) * ACC_STRIDE + w * 12;
    ((float4*)orow)[0] = make_float4(acc[0], acc[1], acc[2], acc[3]);
    ((float4*)orow)[1] = make_float4(acc[4], acc[5], acc[6], acc[7]);
    ((float4*)orow)[2] = make_float4(acc[8], acc[9], acc[10], acc[11]);
    if (w == 0)
        accWs[((size_t)split * N + i0 + lane) * ACC_STRIDE + 48] = lsum;
}

// ---------------- Kernel 3: reduce splits + LayerNorm + MLP 48->256->128->32
__global__ __launch_bounds__(256) void k_mlp(const float* __restrict__ accWs,
                                             const float* __restrict__ gamma,
                                             const float* __restrict__ beta,
                                             const float* __restrict__ W1, const float* __restrict__ b1,
                                             const float* __restrict__ W2, const float* __restrict__ b2,
                                             const float* __restrict__ W3, const float* __restrict__ b3,
                                             float* __restrict__ out) {
    __shared__ float hacc[RB * 49];
    __shared__ float hN[RB * DH];
    __shared__ float h1[RB * 256];
    __shared__ float h2[RB * 128];
    int t = threadIdx.x;
    int r0 = blockIdx.x * RB;

    // reduce K-split partials
    for (int e = t; e < RB * 49; e += 256) {
        int r = e / 49, d = e % 49;
        size_t base = (size_t)(r0 + r) * ACC_STRIDE + d;
        float v = 0.f;
        #pragma unroll
        for (int sp = 0; sp < NSPLIT; ++sp)
            v += accWs[(size_t)sp * N * ACC_STRIDE + base];
        hacc[r * 49 + d] = v;
    }
    __syncthreads();

    // LayerNorm (two-pass), h' = acc / l
    if (t < RB) {
        float invl = 1.f / hacc[t * 49 + 48];
        float sum = 0.f;
        for (int d = 0; d < DH; ++d) sum += hacc[t * 49 + d];
        float mean = sum * invl * (1.f / DH);
        float var = 0.f;
        for (int d = 0; d < DH; ++d) {
            float dv = hacc[t * 49 + d] * invl - mean;
            var += dv * dv;
        }
        var *= (1.f / DH);
        float rs = rsqrtf(var + 1e-5f);
        for (int d = 0; d < DH; ++d) {
            float hv = (hacc[t * 49 + d] * invl - mean) * rs;
            hN[t * DH + d] = hv * gamma[d] + beta[d];
        }
    }
    __syncthreads();

    // MLP1: 48 -> 256, thread t = output channel, loops rows
    {
        int c = t;
        float wreg[48];
        const float4* wrow = (const float4*)(W1 + c * DH);
        #pragma unroll
        for (int k4 = 0; k4 < 12; ++k4) {
            float4 v = wrow[k4];
            wreg[k4 * 4 + 0] = v.x; wreg[k4 * 4 + 1] = v.y;
            wreg[k4 * 4 + 2] = v.z; wreg[k4 * 4 + 3] = v.w;
        }
        float bias = b1[c];
        for (int r = 0; r < RB; ++r) {
            float acc = bias;
            #pragma unroll
            for (int k = 0; k < DH; ++k) acc += hN[r * DH + k] * wreg[k];
            h1[r * 256 + c] = fmaxf(acc, 0.f);
        }
    }
    __syncthreads();

    // MLP2: 256 -> 128, (c = t&127, half the rows each)
    {
        int c = t & 127;
        int g = t >> 7;
        int rb = g * 16;
        float acc[16];
        float bias = b2[c];
        #pragma unroll
        for (int r = 0; r < 16; ++r) acc[r] = bias;
        const float4* wrow = (const float4*)(W2 + c * 256);
        for (int k4 = 0; k4 < 64; ++k4) {
            float4 wv = wrow[k4];
            #pragma unroll
            for (int r = 0; r < 16; ++r) {
                const float4 hv = *(const float4*)(&h1[(rb + r) * 256 + k4 * 4]);
                acc[r] += wv.x * hv.x + wv.y * hv.y + wv.z * hv.z + wv.w * hv.w;
            }
        }
        #pragma unroll
        for (int r = 0; r < 16; ++r)
            h2[(rb + r) * 128 + c] = fmaxf(acc[r], 0.f);
    }
    __syncthreads();

    // MLP3: 128 -> 32
    {
        int c = t & 31;
        int g = t >> 5;
        int rb = g * 4;
        float acc[4];
        float bias = b3[c];
        #pragma unroll
        for (int r = 0; r < 4; ++r) acc[r] = bias;
        const float4* wrow = (const float4*)(W3 + c * 128);
        for (int k4 = 0; k4 < 32; ++k4) {
            float4 wv = wrow[k4];
            #pragma unroll
            for (int r = 0; r < 4; ++r) {
                const float4 hv = *(const float4*)(&h2[(rb + r) * 128 + k4 * 4]);
                acc[r] += wv.x * hv.x + wv.y * hv.y + wv.z * hv.z + wv.w * hv.w;
            }
        }
        #pragma unroll
        for (int r = 0; r < 4; ++r)
            out[(size_t)(r0 + rb + r) * 32 + c] = acc[r];
    }
}

extern "C" void kernel_launch(void* const* d_in, const int* in_sizes, int n_in,
                              void* d_out, int out_size, void* d_ws, size_t ws_size,
                              hipStream_t stream) {
    const float* x     = (const float*)d_in[0];
    const int*   adj   = (const int*)d_in[1];
    const float* Wg    = (const float*)d_in[2];
    const float* a     = (const float*)d_in[3];
    const float* gamma = (const float*)d_in[4];
    const float* beta  = (const float*)d_in[5];
    const float* W1    = (const float*)d_in[6];
    const float* b1    = (const float*)d_in[7];
    const float* W2    = (const float*)d_in[8];
    const float* b2    = (const float*)d_in[9];
    const float* W3    = (const float*)d_in[10];
    const float* b3    = (const float*)d_in[11];
    float* out = (float*)d_out;

    float* ws = (float*)d_ws;
    float* Wh    = ws;                          // 8192*48
    float* s     = ws + (size_t)N * DH;         // 8192
    float* accWs = s + N;                       // NSPLIT*8192*52

    k_wh<<<N * DH / 256, 256, 0, stream>>>(x, Wg, Wh);
    k_s<<<N / 256, 256, 0, stream>>>(Wh, a, s);
    k_gat<<<(N / MT) * NSPLIT, 256, 0, stream>>>(adj, Wh, s, accWs);
    k_mlp<<<N / RB, 256, 0, stream>>>(accWs, gamma, beta, W1, b1, W2, b2, W3, b3, out);
}

// Round 2
// 495.016 us; speedup vs baseline: 1.5321x; 1.5321x over previous
//
#include <hip/hip_runtime.h>

#define N 8192
#define DIN 128
#define DH 48
#define MT 256           // rows per k_gat block
#define KC 64            // j-chunk
#define PSTR (MT + 4)    // pT row stride (floats): +4 keeps b128 align, 8-way min conflict
#define ACC_STRIDE 52    // 48 dims + l, padded to 16B multiple
#define RB 32            // rows per k_mlp block

// ---------------- Kernel 1a: Wh = x @ Wgat^T  [8192,128]x[48,128] -> [8192,48]
__global__ __launch_bounds__(256) void k_wh(const float* __restrict__ x,
                                            const float* __restrict__ Wg,
                                            float* __restrict__ Wh) {
    __shared__ float wT[DIN * DH];  // transposed: wT[k*DH + c] = Wg[c*DIN + k]
    int t = threadIdx.x;
    for (int e = t; e < DIN * DH; e += 256) {
        int c = e / DIN, k = e % DIN;
        wT[k * DH + c] = Wg[e];
    }
    __syncthreads();
    int o = blockIdx.x * 256 + t;      // o < 8192*48
    int r = o / DH, c = o % DH;
    const float4* xr = (const float4*)(x + (size_t)r * DIN);
    float acc = 0.f;
    #pragma unroll 8
    for (int k4 = 0; k4 < DIN / 4; ++k4) {
        float4 xv = xr[k4];
        int kb = k4 * 4;
        acc += xv.x * wT[(kb + 0) * DH + c];
        acc += xv.y * wT[(kb + 1) * DH + c];
        acc += xv.z * wT[(kb + 2) * DH + c];
        acc += xv.w * wT[(kb + 3) * DH + c];
    }
    Wh[o] = acc;
}

// ---------------- Kernel 1b: s = Wh @ a^T
__global__ __launch_bounds__(256) void k_s(const float* __restrict__ Wh,
                                           const float* __restrict__ a,
                                           float* __restrict__ s) {
    int r = blockIdx.x * 256 + threadIdx.x;
    const float4* wr = (const float4*)(Wh + (size_t)r * DH);
    const float4* av = (const float4*)a;
    float acc = 0.f;
    #pragma unroll
    for (int k4 = 0; k4 < DH / 4; ++k4) {
        float4 w = wr[k4]; float4 aa = av[k4];
        acc += w.x * aa.x + w.y * aa.y + w.z * aa.z + w.w * aa.w;
    }
    s[r] = acc;
}

// ---------------- Kernel 2: fused masked-softmax attention.
// No max-subtraction needed (e bounded ~|2|); masked entries contribute exact 0.
// Block: 256 rows x jspan j's, K-split partial sums into accWs.
// Thread MAC tile: 4 rows (lane=t&63, contiguous b128 from pT) x 12 dims
// (wave=t>>6, wave-uniform broadcast reads from wS). 48 FMA / ~48 LDS-cyc.
__global__ __launch_bounds__(256) void k_gat(const int* __restrict__ adj,
                                             const float* __restrict__ Wh,
                                             const float* __restrict__ s,
                                             float* __restrict__ accWs,
                                             int jspan, int nchunk) {
    __shared__ float pT[KC][PSTR];     // [j][row], rows contiguous for b128 MAC reads
    __shared__ float wS[KC][DH];       // staged Wh chunk
    __shared__ float sRow[MT];
    int t = threadIdx.x;
    int tile = blockIdx.x & 31;        // 32 row tiles of 256
    int split = blockIdx.x >> 5;
    int i0 = tile * MT;
    int jbase = split * jspan;

    int lane = t & 63;                 // MAC: row pack (4 rows); phase A: j lane
    int w = t >> 6;                    // MAC: 12-dim slice; phase A: row group

    sRow[t] = s[i0 + t];

    float acc[4][12];
    #pragma unroll
    for (int rr = 0; rr < 4; ++rr)
        #pragma unroll
        for (int d = 0; d < 12; ++d) acc[rr][d] = 0.f;
    float lsum[4] = {0.f, 0.f, 0.f, 0.f};

    __syncthreads();

    for (int chunk = 0; chunk < nchunk; ++chunk) {
        int j0 = jbase + chunk * KC;
        // ---- stage Wh chunk -> wS (coalesced, contiguous)
        {
            const float4* wsrc = (const float4*)(Wh + (size_t)j0 * DH);
            float4* wdst = (float4*)&wS[0][0];
            #pragma unroll
            for (int k = 0; k < 3; ++k) wdst[t + k * 256] = wsrc[t + k * 256];
        }
        // ---- phase A: p for 256 rows x 64 j (adj coalesced along j)
        {
            int j = j0 + lane;
            float sj = s[j];
            #pragma unroll 4
            for (int it = 0; it < 16; ++it) {
                int r0 = (w * 16 + it) * 4;
                float4 pv;
                #pragma unroll
                for (int k = 0; k < 4; ++k) {
                    int av = adj[(size_t)(i0 + r0 + k) * N + j];
                    float e = sRow[r0 + k] + sj;
                    e = fmaxf(e, 0.2f * e);               // LeakyReLU(0.2)
                    ((float*)&pv)[k] = (av > 0) ? __expf(e) : 0.f;
                }
                *(float4*)&pT[lane][r0] = pv;             // b128, 8-way bank conflict (16/chunk, cheap)
            }
        }
        __syncthreads();
        // ---- MAC: acc[4 rows][12 dims] += p * w
        {
            const int rbase = lane * 4;
            const int dbase = w * 12;
            #pragma unroll 4
            for (int jj = 0; jj < KC; ++jj) {
                float4 p = *(const float4*)&pT[jj][rbase];
                const float4* wr = (const float4*)&wS[jj][dbase];
                float4 w0 = wr[0], w1 = wr[1], w2 = wr[2];
                #pragma unroll
                for (int rr = 0; rr < 4; ++rr) {
                    float pr = ((const float*)&p)[rr];
                    acc[rr][0] += pr * w0.x; acc[rr][1]  += pr * w0.y;
                    acc[rr][2] += pr * w0.z; acc[rr][3]  += pr * w0.w;
                    acc[rr][4] += pr * w1.x; acc[rr][5]  += pr * w1.y;
                    acc[rr][6] += pr * w1.z; acc[rr][7]  += pr * w1.w;
                    acc[rr][8] += pr * w2.x; acc[rr][9]  += pr * w2.y;
                    acc[rr][10] += pr * w2.z; acc[rr][11] += pr * w2.w;
                }
                if (w == 0) {                              // wave-uniform branch
                    #pragma unroll
                    for (int rr = 0; rr < 4; ++rr)
                        lsum[rr] += ((const float*)&p)[rr];
                }
            }
        }
        __syncthreads();
    }
    // ---- epilogue: partial (acc, l) per split
    size_t base = (size_t)split * N + i0 + lane * 4;
    #pragma unroll
    for (int rr = 0; rr < 4; ++rr) {
        float* orow = accWs + (base + rr) * ACC_STRIDE + w * 12;
        ((float4*)orow)[0] = make_float4(acc[rr][0], acc[rr][1], acc[rr][2], acc[rr][3]);
        ((float4*)orow)[1] = make_float4(acc[rr][4], acc[rr][5], acc[rr][6], acc[rr][7]);
        ((float4*)orow)[2] = make_float4(acc[rr][8], acc[rr][9], acc[rr][10], acc[rr][11]);
        if (w == 0)
            accWs[(base + rr) * ACC_STRIDE + 48] = lsum[rr];
    }
}

// ---------------- Kernel 3: reduce splits + LayerNorm + MLP 48->256->128->32
__global__ __launch_bounds__(256) void k_mlp(const float* __restrict__ accWs,
                                             const float* __restrict__ gamma,
                                             const float* __restrict__ beta,
                                             const float* __restrict__ W1, const float* __restrict__ b1,
                                             const float* __restrict__ W2, const float* __restrict__ b2,
                                             const float* __restrict__ W3, const float* __restrict__ b3,
                                             float* __restrict__ out, int nsplit) {
    __shared__ float hacc[RB * 49];
    __shared__ float hN[RB * DH];
    __shared__ float h1[RB * 256];
    __shared__ float h2[RB * 128];
    int t = threadIdx.x;
    int r0 = blockIdx.x * RB;

    // reduce K-split partials
    for (int e = t; e < RB * 49; e += 256) {
        int r = e / 49, d = e % 49;
        size_t base = (size_t)(r0 + r) * ACC_STRIDE + d;
        float v = 0.f;
        for (int sp = 0; sp < nsplit; ++sp)
            v += accWs[(size_t)sp * N * ACC_STRIDE + base];
        hacc[r * 49 + d] = v;
    }
    __syncthreads();

    // LayerNorm (two-pass), h' = acc / l
    if (t < RB) {
        float invl = 1.f / hacc[t * 49 + 48];
        float sum = 0.f;
        for (int d = 0; d < DH; ++d) sum += hacc[t * 49 + d];
        float mean = sum * invl * (1.f / DH);
        float var = 0.f;
        for (int d = 0; d < DH; ++d) {
            float dv = hacc[t * 49 + d] * invl - mean;
            var += dv * dv;
        }
        var *= (1.f / DH);
        float rs = rsqrtf(var + 1e-5f);
        for (int d = 0; d < DH; ++d) {
            float hv = (hacc[t * 49 + d] * invl - mean) * rs;
            hN[t * DH + d] = hv * gamma[d] + beta[d];
        }
    }
    __syncthreads();

    // MLP1: 48 -> 256, thread t = output channel, loops rows
    {
        int c = t;
        float4 wreg[12];
        const float4* wrow = (const float4*)(W1 + c * DH);
        #pragma unroll
        for (int k4 = 0; k4 < 12; ++k4) wreg[k4] = wrow[k4];
        float bias = b1[c];
        for (int r = 0; r < RB; ++r) {
            float acc = bias;
            const float4* hv4 = (const float4*)&hN[r * DH];
            #pragma unroll
            for (int k4 = 0; k4 < 12; ++k4) {
                float4 hv = hv4[k4];
                acc += hv.x * wreg[k4].x + hv.y * wreg[k4].y
                     + hv.z * wreg[k4].z + hv.w * wreg[k4].w;
            }
            h1[r * 256 + c] = fmaxf(acc, 0.f);
        }
    }
    __syncthreads();

    // MLP2: 256 -> 128 (c = t&127, half the rows each)
    {
        int c = t & 127;
        int g = t >> 7;
        int rb = g * 16;
        float acc[16];
        float bias = b2[c];
        #pragma unroll
        for (int r = 0; r < 16; ++r) acc[r] = bias;
        const float4* wrow = (const float4*)(W2 + c * 256);
        for (int k4 = 0; k4 < 64; ++k4) {
            float4 wv = wrow[k4];
            #pragma unroll
            for (int r = 0; r < 16; ++r) {
                const float4 hv = *(const float4*)(&h1[(rb + r) * 256 + k4 * 4]);
                acc[r] += wv.x * hv.x + wv.y * hv.y + wv.z * hv.z + wv.w * hv.w;
            }
        }
        #pragma unroll
        for (int r = 0; r < 16; ++r)
            h2[(rb + r) * 128 + c] = fmaxf(acc[r], 0.f);
    }
    __syncthreads();

    // MLP3: 128 -> 32
    {
        int c = t & 31;
        int g = t >> 5;
        int rb = g * 4;
        float acc[4];
        float bias = b3[c];
        #pragma unroll
        for (int r = 0; r < 4; ++r) acc[r] = bias;
        const float4* wrow = (const float4*)(W3 + c * 128);
        for (int k4 = 0; k4 < 32; ++k4) {
            float4 wv = wrow[k4];
            #pragma unroll
            for (int r = 0; r < 4; ++r) {
                const float4 hv = *(const float4*)(&h2[(rb + r) * 128 + k4 * 4]);
                acc[r] += wv.x * hv.x + wv.y * hv.y + wv.z * hv.z + wv.w * hv.w;
            }
        }
        #pragma unroll
        for (int r = 0; r < 4; ++r)
            out[(size_t)(r0 + rb + r) * 32 + c] = acc[r];
    }
}

extern "C" void kernel_launch(void* const* d_in, const int* in_sizes, int n_in,
                              void* d_out, int out_size, void* d_ws, size_t ws_size,
                              hipStream_t stream) {
    const float* x     = (const float*)d_in[0];
    const int*   adj   = (const int*)d_in[1];
    const float* Wg    = (const float*)d_in[2];
    const float* a     = (const float*)d_in[3];
    const float* gamma = (const float*)d_in[4];
    const float* beta  = (const float*)d_in[5];
    const float* W1    = (const float*)d_in[6];
    const float* b1    = (const float*)d_in[7];
    const float* W2    = (const float*)d_in[8];
    const float* b2    = (const float*)d_in[9];
    const float* W3    = (const float*)d_in[10];
    const float* b3    = (const float*)d_in[11];
    float* out = (float*)d_out;

    float* ws = (float*)d_ws;
    float* Wh    = ws;                          // 8192*48
    float* s     = ws + (size_t)N * DH;         // 8192
    float* accWs = s + N;                       // nsplit*8192*52

    // pick nsplit by available workspace (16 preferred: 512 blocks = 2/CU)
    size_t avail = ws_size / 4 - ((size_t)N * DH + N);
    int nsplit = (avail >= (size_t)16 * N * ACC_STRIDE) ? 16 : 8;
    int jspan = N / nsplit;
    int nchunk = jspan / KC;

    k_wh<<<N * DH / 256, 256, 0, stream>>>(x, Wg, Wh);
    k_s<<<N / 256, 256, 0, stream>>>(Wh, a, s);
    k_gat<<<32 * nsplit, 256, 0, stream>>>(adj, Wh, s, accWs, jspan, nchunk);
    k_mlp<<<N / RB, 256, 0, stream>>>(accWs, gamma, beta, W1, b1, W2, b2, W3, b3, out, nsplit);
}

// Round 3
// 463.403 us; speedup vs baseline: 1.6366x; 1.0682x over previous
//
#include <hip/hip_runtime.h>

#define N 8192
#define DIN 128
#define DH 48
#define MT 256           // rows per k_gat block
#define KC 64            // j-chunk
#define PSTR (KC + 8)    // f16 row stride: 144 B -> 2-way bank aliasing (free)
#define NSPLIT 16
#define JSPAN (N / NSPLIT)   // 512
#define NCHUNK (JSPAN / KC)  // 8
#define ACC_STRIDE 64    // 48 dims + lsum@48 + 15 unused (MFMA N-tile padding)
#define RB 32            // rows per k_mlp block

typedef _Float16 half8 __attribute__((ext_vector_type(8)));
typedef float f32x4 __attribute__((ext_vector_type(4)));

// ---------------- Kernel 1a: Wh = x @ Wgat^T  [8192,128]x[48,128] -> [8192,48]
__global__ __launch_bounds__(256) void k_wh(const float* __restrict__ x,
                                            const float* __restrict__ Wg,
                                            float* __restrict__ Wh) {
    __shared__ float wT[DIN * DH];  // transposed: wT[k*DH + c] = Wg[c*DIN + k]
    int t = threadIdx.x;
    for (int e = t; e < DIN * DH; e += 256) {
        int c = e / DIN, k = e % DIN;
        wT[k * DH + c] = Wg[e];
    }
    __syncthreads();
    int o = blockIdx.x * 256 + t;      // o < 8192*48
    int r = o / DH, c = o % DH;
    const float4* xr = (const float4*)(x + (size_t)r * DIN);
    float acc = 0.f;
    #pragma unroll 8
    for (int k4 = 0; k4 < DIN / 4; ++k4) {
        float4 xv = xr[k4];
        int kb = k4 * 4;
        acc += xv.x * wT[(kb + 0) * DH + c];
        acc += xv.y * wT[(kb + 1) * DH + c];
        acc += xv.z * wT[(kb + 2) * DH + c];
        acc += xv.w * wT[(kb + 3) * DH + c];
    }
    Wh[o] = acc;
}

// ---------------- Kernel 1b: s = Wh @ a^T
__global__ __launch_bounds__(256) void k_s(const float* __restrict__ Wh,
                                           const float* __restrict__ a,
                                           float* __restrict__ s) {
    int r = blockIdx.x * 256 + threadIdx.x;
    const float4* wr = (const float4*)(Wh + (size_t)r * DH);
    const float4* av = (const float4*)a;
    float acc = 0.f;
    #pragma unroll
    for (int k4 = 0; k4 < DH / 4; ++k4) {
        float4 w = wr[k4]; float4 aa = av[k4];
        acc += w.x * aa.x + w.y * aa.y + w.z * aa.z + w.w * aa.w;
    }
    s[r] = acc;
}

// ---------------- Kernel 2: fused masked-softmax attention, f16-MFMA MAC.
// e = lrelu(s_i+s_j) is bounded (|e|<~2) -> softmax without max-subtraction;
// masked entries contribute exact 0. Partial sums per J-split into accWs.
// P@Wh via mfma_f32_16x16x32_f16: M=256, N=64 (48 dims + ones col for
// lsum + zero pad), K=64/chunk. LDS tiles padded to 72-elem rows (2-way max).
__global__ __launch_bounds__(256) void k_gat(const int* __restrict__ adj,
                                             const float* __restrict__ Wh,
                                             const float* __restrict__ s,
                                             float* __restrict__ accWs) {
    __shared__ _Float16 pS[MT][PSTR];   // A: P[row][j]
    __shared__ _Float16 wS[64][PSTR];   // B^T: wS[d][j]; d=48 ones, 49..63 zero
    __shared__ float sRow[MT];
    int t = threadIdx.x;
    int tile = blockIdx.x & 31;        // 32 row tiles of 256
    int split = blockIdx.x >> 5;       // 0..15
    int i0 = tile * MT;
    int jbase = split * JSPAN;

    sRow[t] = s[i0 + t];
    // init constant B rows (ones col @48, zeros 49..63), incl pad
    for (int e = t; e < 16 * PSTR; e += 256) {
        int n = 48 + e / PSTR, k = e % PSTR;
        wS[n][k] = (n == 48) ? (_Float16)1.0f : (_Float16)0.0f;
    }

    int lane = t & 63, w = t >> 6;
    int ln16 = lane & 15, kq = lane >> 4;   // MFMA lane decomposition
    int jp = t & 31, rg = t >> 5;           // phase A: j-pair, row group

    f32x4 acc[4][4];
    #pragma unroll
    for (int a0 = 0; a0 < 4; ++a0)
        #pragma unroll
        for (int b0 = 0; b0 < 4; ++b0) acc[a0][b0] = (f32x4){0.f, 0.f, 0.f, 0.f};

    __syncthreads();

    for (int chunk = 0; chunk < NCHUNK; ++chunk) {
        int j0 = jbase + chunk * KC;
        // ---- stage Wh chunk transposed -> wS (f16)
        #pragma unroll
        for (int k = 0; k < 12; ++k) {
            int e = t + k * 256;            // e < 3072 = 64*48
            int jc = e / DH, d = e % DH;
            wS[d][jc] = (_Float16)Wh[(size_t)j0 * DH + e];
        }
        // ---- phase A: p (f16) for 256 rows x 64 j; adj coalesced along j
        {
            float2 sj = *(const float2*)(s + j0 + 2 * jp);
            #pragma unroll 8
            for (int it = 0; it < 32; ++it) {
                int r = rg * 32 + it;
                int2 av = *(const int2*)(adj + (size_t)(i0 + r) * N + j0 + 2 * jp);
                float e0 = sRow[r] + sj.x;
                float e1 = sRow[r] + sj.y;
                e0 = fmaxf(e0, 0.2f * e0);              // LeakyReLU(0.2)
                e1 = fmaxf(e1, 0.2f * e1);
                float p0 = av.x ? __expf(e0) : 0.f;     // masked -> exact 0
                float p1 = av.y ? __expf(e1) : 0.f;
                union { _Float16 h[2]; unsigned u; } pk;
                pk.h[0] = (_Float16)p0;                 // RTN
                pk.h[1] = (_Float16)p1;
                *(unsigned*)&pS[r][2 * jp] = pk.u;
            }
        }
        __syncthreads();
        // ---- MFMA MAC: wave w owns M-tiles w*4..w*4+3, all 4 N-tiles
        {
            const int m0 = w * 64;
            #pragma unroll
            for (int kt = 0; kt < 2; ++kt) {
                const int kk = kt * 32 + kq * 8;
                half8 b[4];
                #pragma unroll
                for (int nt = 0; nt < 4; ++nt)
                    b[nt] = *(const half8*)&wS[nt * 16 + ln16][kk];
                #pragma unroll
                for (int mtl = 0; mtl < 4; ++mtl) {
                    half8 a = *(const half8*)&pS[m0 + mtl * 16 + ln16][kk];
                    #pragma unroll
                    for (int nt = 0; nt < 4; ++nt)
                        acc[mtl][nt] = __builtin_amdgcn_mfma_f32_16x16x32_f16(
                            a, b[nt], acc[mtl][nt], 0, 0, 0);
                }
            }
        }
        __syncthreads();
    }
    // ---- epilogue: C/D layout col=lane&15, row=kq*4+reg
    size_t rbase = (size_t)split * N + i0;
    #pragma unroll
    for (int mtl = 0; mtl < 4; ++mtl) {
        #pragma unroll
        for (int nt = 0; nt < 4; ++nt) {
            int col = nt * 16 + ln16;
            if (nt == 3 && ln16 != 0) continue;   // only col 48 (lsum) useful
            #pragma unroll
            for (int reg = 0; reg < 4; ++reg) {
                int row = w * 64 + mtl * 16 + kq * 4 + reg;
                accWs[(rbase + row) * ACC_STRIDE + col] = acc[mtl][nt][reg];
            }
        }
    }
}

// ---------------- Kernel 3: reduce splits + LayerNorm + MLP 48->256->128->32
__global__ __launch_bounds__(256) void k_mlp(const float* __restrict__ accWs,
                                             const float* __restrict__ gamma,
                                             const float* __restrict__ beta,
                                             const float* __restrict__ W1, const float* __restrict__ b1,
                                             const float* __restrict__ W2, const float* __restrict__ b2,
                                             const float* __restrict__ W3, const float* __restrict__ b3,
                                             float* __restrict__ out) {
    __shared__ float hacc[RB * 49];
    __shared__ float hN[RB * DH];
    __shared__ float h1[RB * 256];
    __shared__ float h2[RB * 128];
    int t = threadIdx.x;
    int r0 = blockIdx.x * RB;

    // reduce K-split partials (d: 0..47 dims, 48 = lsum)
    for (int e = t; e < RB * 49; e += 256) {
        int r = e / 49, d = e % 49;
        size_t base = (size_t)(r0 + r) * ACC_STRIDE + d;
        float v = 0.f;
        #pragma unroll
        for (int sp = 0; sp < NSPLIT; ++sp)
            v += accWs[(size_t)sp * N * ACC_STRIDE + base];
        hacc[r * 49 + d] = v;
    }
    __syncthreads();

    // LayerNorm (two-pass), h' = acc / l
    if (t < RB) {
        float invl = 1.f / hacc[t * 49 + 48];
        float sum = 0.f;
        for (int d = 0; d < DH; ++d) sum += hacc[t * 49 + d];
        float mean = sum * invl * (1.f / DH);
        float var = 0.f;
        for (int d = 0; d < DH; ++d) {
            float dv = hacc[t * 49 + d] * invl - mean;
            var += dv * dv;
        }
        var *= (1.f / DH);
        float rs = rsqrtf(var + 1e-5f);
        for (int d = 0; d < DH; ++d) {
            float hv = (hacc[t * 49 + d] * invl - mean) * rs;
            hN[t * DH + d] = hv * gamma[d] + beta[d];
        }
    }
    __syncthreads();

    // MLP1: 48 -> 256, thread t = output channel, loops rows
    {
        int c = t;
        float4 wreg[12];
        const float4* wrow = (const float4*)(W1 + c * DH);
        #pragma unroll
        for (int k4 = 0; k4 < 12; ++k4) wreg[k4] = wrow[k4];
        float bias = b1[c];
        for (int r = 0; r < RB; ++r) {
            float acc = bias;
            const float4* hv4 = (const float4*)&hN[r * DH];
            #pragma unroll
            for (int k4 = 0; k4 < 12; ++k4) {
                float4 hv = hv4[k4];
                acc += hv.x * wreg[k4].x + hv.y * wreg[k4].y
                     + hv.z * wreg[k4].z + hv.w * wreg[k4].w;
            }
            h1[r * 256 + c] = fmaxf(acc, 0.f);
        }
    }
    __syncthreads();

    // MLP2: 256 -> 128 (c = t&127, half the rows each)
    {
        int c = t & 127;
        int g = t >> 7;
        int rb = g * 16;
        float acc[16];
        float bias = b2[c];
        #pragma unroll
        for (int r = 0; r < 16; ++r) acc[r] = bias;
        const float4* wrow = (const float4*)(W2 + c * 256);
        for (int k4 = 0; k4 < 64; ++k4) {
            float4 wv = wrow[k4];
            #pragma unroll
            for (int r = 0; r < 16; ++r) {
                const float4 hv = *(const float4*)(&h1[(rb + r) * 256 + k4 * 4]);
                acc[r] += wv.x * hv.x + wv.y * hv.y + wv.z * hv.z + wv.w * hv.w;
            }
        }
        #pragma unroll
        for (int r = 0; r < 16; ++r)
            h2[(rb + r) * 128 + c] = fmaxf(acc[r], 0.f);
    }
    __syncthreads();

    // MLP3: 128 -> 32
    {
        int c = t & 31;
        int g = t >> 5;
        int rb = g * 4;
        float acc[4];
        float bias = b3[c];
        #pragma unroll
        for (int r = 0; r < 4; ++r) acc[r] = bias;
        const float4* wrow = (const float4*)(W3 + c * 128);
        for (int k4 = 0; k4 < 32; ++k4) {
            float4 wv = wrow[k4];
            #pragma unroll
            for (int r = 0; r < 4; ++r) {
                const float4 hv = *(const float4*)(&h2[(rb + r) * 128 + k4 * 4]);
                acc[r] += wv.x * hv.x + wv.y * hv.y + wv.z * hv.z + wv.w * hv.w;
            }
        }
        #pragma unroll
        for (int r = 0; r < 4; ++r)
            out[(size_t)(r0 + rb + r) * 32 + c] = acc[r];
    }
}

extern "C" void kernel_launch(void* const* d_in, const int* in_sizes, int n_in,
                              void* d_out, int out_size, void* d_ws, size_t ws_size,
                              hipStream_t stream) {
    const float* x     = (const float*)d_in[0];
    const int*   adj   = (const int*)d_in[1];
    const float* Wg    = (const float*)d_in[2];
    const float* a     = (const float*)d_in[3];
    const float* gamma = (const float*)d_in[4];
    const float* beta  = (const float*)d_in[5];
    const float* W1    = (const float*)d_in[6];
    const float* b1    = (const float*)d_in[7];
    const float* W2    = (const float*)d_in[8];
    const float* b2    = (const float*)d_in[9];
    const float* W3    = (const float*)d_in[10];
    const float* b3    = (const float*)d_in[11];
    float* out = (float*)d_out;

    float* ws = (float*)d_ws;
    float* Wh    = ws;                          // 8192*48
    float* s     = ws + (size_t)N * DH;         // 8192
    float* accWs = s + N;                       // NSPLIT*8192*64 = 33.5 MB

    k_wh<<<N * DH / 256, 256, 0, stream>>>(x, Wg, Wh);
    k_s<<<N / 256, 256, 0, stream>>>(Wh, a, s);
    k_gat<<<32 * NSPLIT, 256, 0, stream>>>(adj, Wh, s, accWs);
    k_mlp<<<N / RB, 256, 0, stream>>>(accWs, gamma, beta, W1, b1, W2, b2, W3, b3, out);
}